// Round 4
// baseline (2617.024 us; speedup 1.0000x reference)
//
#include <hip/hip_runtime.h>
#include <hip/hip_fp16.h>

// Sinkhorn OT: n=m=4096, d=32, reg=0.1, 100 iterations, uniform marginals.
// R4: single persistent kernel, 256 WGs x 1024 thr (one per CU, co-resident
// by capacity). WG b owns rows [16b,16b+16) of Kh (fp16, 128KB) -> 4MB per
// XCD = L2-resident across all 100 iterations. Column pass = per-WG partial
// colsums over owned rows (L2-hot) + hierarchical reduce. Cross-WG data
// (v, partials, barrier ctr) uses ONLY relaxed agent-scope atomics
// (sc-coherent, bypass L2) so no fence ever invalidates the cached K lines.
// Release ordering comes from __syncthreads' implicit vmcnt(0) drain before
// each barrier arrival.

#define NN 4096
#define MM 4096
#define DD 32
#define N_ITERS 100

static constexpr float INV_REG = 10.0f;
static constexpr float A_MARG  = 1.0f / 4096.0f;
static constexpr float B_MARG  = 1.0f / 4096.0f;

typedef _Float16 h2_t __attribute__((ext_vector_type(2)));

static __device__ __forceinline__ float dot2(unsigned a, unsigned b, float acc) {
#if __has_builtin(__builtin_amdgcn_fdot2)
    return __builtin_amdgcn_fdot2(__builtin_bit_cast(h2_t, a),
                                  __builtin_bit_cast(h2_t, b), acc, false);
#else
    float2 fa = __half22float2(*(const __half2*)&a);
    float2 fb = __half22float2(*(const __half2*)&b);
    acc = fmaf(fa.x, fb.x, acc);
    return fmaf(fa.y, fb.y, acc);
#endif
}

// --- relaxed agent-scope (device-coherent, L2-bypassing) accessors --------
static __device__ __forceinline__ float ld_dev_f32(const float* p) {
    return __hip_atomic_load(p, __ATOMIC_RELAXED, __HIP_MEMORY_SCOPE_AGENT);
}
static __device__ __forceinline__ void st_dev_f32(float* p, float v) {
    __hip_atomic_store(p, v, __ATOMIC_RELAXED, __HIP_MEMORY_SCOPE_AGENT);
}
static __device__ __forceinline__ unsigned long long ld_dev_u64(const unsigned long long* p) {
    return __hip_atomic_load(p, __ATOMIC_RELAXED, __HIP_MEMORY_SCOPE_AGENT);
}
static __device__ __forceinline__ void st_dev_u64(unsigned long long* p, unsigned long long v) {
    __hip_atomic_store(p, v, __ATOMIC_RELAXED, __HIP_MEMORY_SCOPE_AGENT);
}
static __device__ __forceinline__ void st_dev_u16(unsigned short* p, unsigned short v) {
    __hip_atomic_store(p, v, __ATOMIC_RELAXED, __HIP_MEMORY_SCOPE_AGENT);
}
static __device__ __forceinline__ unsigned ld_dev_u32(const unsigned* p) {
    return __hip_atomic_load(p, __ATOMIC_RELAXED, __HIP_MEMORY_SCOPE_AGENT);
}

// ---------------------------------------------------------------------------
// Kh[i][j] = (half)exp(-||x_i - y_j||^2 / reg). Also primes v16 = 1/4096 and
// zeroes the barrier counter (d_ws is re-poisoned before every launch!).
// grid: (16, 256), block 256
// ---------------------------------------------------------------------------
__global__ void compute_K_half(const float* __restrict__ x, const float* __restrict__ y,
                               __half* __restrict__ Kh, __half* __restrict__ v16,
                               unsigned* __restrict__ ctr) {
    const int tid = threadIdx.x;
    const int j   = blockIdx.x * 256 + tid;
    const int r0  = blockIdx.y * 16;

    if (blockIdx.y == 0) {
        v16[j] = __float2half(B_MARG);
        if (blockIdx.x == 0 && tid == 0) *ctr = 0u;
    }

    float yv[DD];
    const float4* y4 = (const float4*)(y + (size_t)j * DD);
#pragma unroll
    for (int k = 0; k < DD / 4; ++k) {
        float4 t = y4[k];
        yv[4 * k + 0] = t.x; yv[4 * k + 1] = t.y;
        yv[4 * k + 2] = t.z; yv[4 * k + 3] = t.w;
    }

    __shared__ float xs[16 * DD];
    xs[tid]       = x[(size_t)r0 * DD + tid];
    xs[tid + 256] = x[(size_t)r0 * DD + tid + 256];
    __syncthreads();

#pragma unroll 4
    for (int ii = 0; ii < 16; ++ii) {
        float acc = 0.0f;
#pragma unroll
        for (int k = 0; k < DD; ++k) {
            float d = xs[ii * DD + k] - yv[k];
            acc = fmaf(d, d, acc);
        }
        Kh[(size_t)(r0 + ii) * MM + j] = __float2half(__expf(-acc * INV_REG));
    }
}

// ---------------------------------------------------------------------------
// Persistent Sinkhorn loop. 256 WGs x 1024 threads (16 waves).
// ---------------------------------------------------------------------------
__global__ void __launch_bounds__(1024, 4)
sinkhorn_persist(const __half* __restrict__ Kh, __half* __restrict__ v16g,
                 float* __restrict__ u32g, float* __restrict__ v32g,
                 float* __restrict__ partial, unsigned* __restrict__ ctr) {
    __shared__ __align__(16) __half v_lds[MM];   // 8 KB
    __shared__ float u_lds[16];
    __shared__ float red[16 * 16];               // [wave][col_local]

    const int tid  = threadIdx.x;
    const int b    = blockIdx.x;
    const int wave = tid >> 6;
    const int lane = tid & 63;
    unsigned bar = 0;

    for (int t = 0; t < N_ITERS; ++t) {
        // ---- stage v (fp16, 8KB) into LDS via coherent 8B loads ----------
        ((unsigned long long*)v_lds)[tid] =
            ld_dev_u64((const unsigned long long*)v16g + tid);
        __syncthreads();

        // ---- sweep A: u_i = a / (Kh[i,:] . v), one owned row per wave ----
        {
            const int i = b * 16 + wave;
            const uint4* Krow = (const uint4*)(Kh + (size_t)i * MM);  // L2-resident
            const uint4* V    = (const uint4*)v_lds;
            float acc = 0.0f;
#pragma unroll
            for (int c = 0; c < 8; ++c) {
                const int g = c * 64 + lane;
                uint4 kk = Krow[g];
                uint4 vv = V[g];
                acc = dot2(kk.x, vv.x, acc);
                acc = dot2(kk.y, vv.y, acc);
                acc = dot2(kk.z, vv.z, acc);
                acc = dot2(kk.w, vv.w, acc);
            }
#pragma unroll
            for (int off = 32; off > 0; off >>= 1) acc += __shfl_down(acc, off, 64);
            if (lane == 0) {
                float u = A_MARG / acc;
                u_lds[wave] = u;
                st_dev_f32(u32g + i, u);
            }
        }
        __syncthreads();

        // ---- sweep B: partial[b][j] = sum_{r<16} u_r * Kh[16b+r][j] ------
        // wave w covers cols [256w, 256w+256), 4 cols/lane (uint2 = 4 halves)
        {
            const int j0 = wave * 256 + lane * 4;
            const __half* base = Kh + (size_t)(b * 16) * MM + j0;
            float a0 = 0.f, a1 = 0.f, a2 = 0.f, a3 = 0.f;
#pragma unroll
            for (int r = 0; r < 16; ++r) {
                uint2 k2 = *(const uint2*)(base + (size_t)r * MM);   // L2-hit
                const float u = u_lds[r];
                float2 f01 = __half22float2(*(const __half2*)&k2.x);
                float2 f23 = __half22float2(*(const __half2*)&k2.y);
                a0 = fmaf(f01.x, u, a0);
                a1 = fmaf(f01.y, u, a1);
                a2 = fmaf(f23.x, u, a2);
                a3 = fmaf(f23.y, u, a3);
            }
            float* pp = partial + (size_t)b * MM + j0;
            float2 p01 = make_float2(a0, a1), p23 = make_float2(a2, a3);
            st_dev_u64((unsigned long long*)pp,
                       __builtin_bit_cast(unsigned long long, p01));
            st_dev_u64((unsigned long long*)(pp + 2),
                       __builtin_bit_cast(unsigned long long, p23));
        }

        // ---- grid barrier 1 (syncthreads drains vmcnt -> stores visible) -
        ++bar;
        __syncthreads();
        if (tid == 0) {
            __hip_atomic_fetch_add(ctr, 1u, __ATOMIC_RELAXED, __HIP_MEMORY_SCOPE_AGENT);
            while (ld_dev_u32(ctr) < 256u * bar) __builtin_amdgcn_s_sleep(2);
        }
        __syncthreads();

        // ---- reduce: v_c = b / sum_wg partial[wg][c], c in [16b, 16b+16) -
        {
            const int cl = tid & 15;           // col within our 16
            const int s  = tid >> 4;           // 0..63 over wg dimension
            const int c  = b * 16 + cl;
            float ps = 0.0f;
#pragma unroll
            for (int k = 0; k < 4; ++k)
                ps += ld_dev_f32(partial + (size_t)(s + 64 * k) * MM + c);
            // in-wave: lanes are {s0..s0+3} x 16 cols; fold the 4 s-values
            ps += __shfl_down(ps, 32, 64);
            ps += __shfl_down(ps, 16, 64);
            if (lane < 16) red[wave * 16 + lane] = ps;   // lane==cl here
            __syncthreads();
            if (wave == 0 && lane < 16) {
                float cs = 0.0f;
#pragma unroll
                for (int q = 0; q < 16; ++q) cs += red[q * 16 + lane];
                float v = B_MARG / cs;
                st_dev_f32(v32g + b * 16 + lane, v);
                st_dev_u16((unsigned short*)(v16g + b * 16 + lane),
                           __builtin_bit_cast(unsigned short, __float2half(v)));
            }
        }

        // ---- grid barrier 2 ---------------------------------------------
        ++bar;
        __syncthreads();
        if (tid == 0) {
            __hip_atomic_fetch_add(ctr, 1u, __ATOMIC_RELAXED, __HIP_MEMORY_SCOPE_AGENT);
            while (ld_dev_u32(ctr) < 256u * bar) __builtin_amdgcn_s_sleep(2);
        }
        __syncthreads();
    }
}

// ---------------------------------------------------------------------------
// gamma[i][j] = u[i] * exp(-||x_i-y_j||^2/reg) * v[j]   (exact fp32 K)
// grid: (16, 256), block 256
// ---------------------------------------------------------------------------
__global__ void epilogue(const float* __restrict__ x, const float* __restrict__ y,
                         const float* __restrict__ u, const float* __restrict__ v,
                         float* __restrict__ out) {
    const int tid = threadIdx.x;
    const int j   = blockIdx.x * 256 + tid;
    const int r0  = blockIdx.y * 16;

    float yv[DD];
    const float4* y4 = (const float4*)(y + (size_t)j * DD);
#pragma unroll
    for (int k = 0; k < DD / 4; ++k) {
        float4 t = y4[k];
        yv[4 * k + 0] = t.x; yv[4 * k + 1] = t.y;
        yv[4 * k + 2] = t.z; yv[4 * k + 3] = t.w;
    }

    __shared__ float xs[16 * DD];
    __shared__ float u_lds[16];
    xs[tid]       = x[(size_t)r0 * DD + tid];
    xs[tid + 256] = x[(size_t)r0 * DD + tid + 256];
    if (tid < 16) u_lds[tid] = u[r0 + tid];
    __syncthreads();

    const float vj = v[j];
#pragma unroll 4
    for (int ii = 0; ii < 16; ++ii) {
        float acc = 0.0f;
#pragma unroll
        for (int k = 0; k < DD; ++k) {
            float d = xs[ii * DD + k] - yv[k];
            acc = fmaf(d, d, acc);
        }
        out[(size_t)(r0 + ii) * MM + j] = u_lds[ii] * __expf(-acc * INV_REG) * vj;
    }
}

extern "C" void kernel_launch(void* const* d_in, const int* in_sizes, int n_in,
                              void* d_out, int out_size, void* d_ws, size_t ws_size,
                              hipStream_t stream) {
    const float* x = (const float*)d_in[0];
    const float* y = (const float*)d_in[1];
    __half*   Kh      = (__half*)d_ws;                       // 32 MB
    float*    partial = (float*)(Kh + (size_t)NN * MM);      // 4 MB
    float*    u32g    = partial + 256 * MM;                  // 16 KB
    float*    v32g    = u32g + NN;                           // 16 KB
    __half*   v16g    = (__half*)(v32g + MM);                // 8 KB
    unsigned* ctr     = (unsigned*)(v16g + MM);              // 4 B
    float*    out     = (float*)d_out;

    compute_K_half<<<dim3(MM / 256, NN / 16), 256, 0, stream>>>(x, y, Kh, v16g, ctr);
    sinkhorn_persist<<<256, 1024, 0, stream>>>(Kh, v16g, u32g, v32g, partial, ctr);
    epilogue<<<dim3(MM / 256, NN / 16), 256, 0, stream>>>(x, y, u32g, v32g, out);
}

// Round 5
// 952.534 us; speedup vs baseline: 2.7474x; 2.7474x over previous
//
#include <hip/hip_runtime.h>
#include <hip/hip_fp16.h>

// Sinkhorn OT: n=m=4096, d=32, reg=0.1, 100 iterations, uniform marginals.
// R5 = R3 (best: fp16 K + K^T, 200 streaming rowpasses) + EXACT-FREEZE early
// termination. The full iteration state is the fp16 v-vector (8KB): once
// v16(t) == v16(t-2) bitwise (fixpoint or 2-cycle), all remaining iterations
// are bit-identical (detect at odd t; 99 odd => v(99)=v(t), u(99)=u(t)), so
// skipping them is exact. Detection via an 8KB parity-history buffer +
// changed-slot + sticky converged flag (relaxed agent-scope atomics).
// ws re-poison 0xAA is a safe hist init: sign bit set => never equals v>0.

#define NN 4096
#define MM 4096
#define DD 32
#define N_ITERS 100

static constexpr float INV_REG = 10.0f;
static constexpr float A_MARG  = 1.0f / 4096.0f;
static constexpr float B_MARG  = 1.0f / 4096.0f;

typedef _Float16 h2_t __attribute__((ext_vector_type(2)));

static __device__ __forceinline__ float dot2(unsigned a, unsigned b, float acc) {
#if __has_builtin(__builtin_amdgcn_fdot2)
    return __builtin_amdgcn_fdot2(__builtin_bit_cast(h2_t, a),
                                  __builtin_bit_cast(h2_t, b), acc, false);
#else
    float2 fa = __half22float2(*(const __half2*)&a);
    float2 fb = __half22float2(*(const __half2*)&b);
    acc = fmaf(fa.x, fb.x, acc);
    return fmaf(fa.y, fb.y, acc);
#endif
}

static __device__ __forceinline__ unsigned ld_dev_u32(const unsigned* p) {
    return __hip_atomic_load(p, __ATOMIC_RELAXED, __HIP_MEMORY_SCOPE_AGENT);
}
static __device__ __forceinline__ void st_dev_u32(unsigned* p, unsigned v) {
    __hip_atomic_store(p, v, __ATOMIC_RELAXED, __HIP_MEMORY_SCOPE_AGENT);
}
static __device__ __forceinline__ unsigned short ld_dev_u16(const unsigned short* p) {
    return __hip_atomic_load(p, __ATOMIC_RELAXED, __HIP_MEMORY_SCOPE_AGENT);
}
static __device__ __forceinline__ void st_dev_u16(unsigned short* p, unsigned short v) {
    __hip_atomic_store(p, v, __ATOMIC_RELAXED, __HIP_MEMORY_SCOPE_AGENT);
}

// ---------------------------------------------------------------------------
// Kh[i][j] = (half)exp(-||p_i - q_j||^2 / reg). prime!=0: v16=1/4096,
// conv=0, slot=1 (slot must start nonzero; 0 means "no change observed").
// grid: (4096/256, 4096/16), block 256
// ---------------------------------------------------------------------------
__global__ void compute_K_half(const float* __restrict__ p, const float* __restrict__ q,
                               __half* __restrict__ Kh, __half* __restrict__ v16,
                               unsigned* __restrict__ conv, unsigned* __restrict__ slot,
                               int prime) {
    const int tid = threadIdx.x;
    const int j   = blockIdx.x * 256 + tid;
    const int r0  = blockIdx.y * 16;

    if (prime && blockIdx.y == 0) {
        v16[j] = __float2half(B_MARG);
        if (blockIdx.x == 0 && tid == 0) { *conv = 0u; *slot = 1u; }
    }

    float qv[DD];
    const float4* q4 = (const float4*)(q + (size_t)j * DD);
#pragma unroll
    for (int k = 0; k < DD / 4; ++k) {
        float4 t = q4[k];
        qv[4 * k + 0] = t.x; qv[4 * k + 1] = t.y;
        qv[4 * k + 2] = t.z; qv[4 * k + 3] = t.w;
    }

    __shared__ float ps[16 * DD];
    ps[tid]       = p[(size_t)r0 * DD + tid];
    ps[tid + 256] = p[(size_t)r0 * DD + tid + 256];
    __syncthreads();

#pragma unroll 4
    for (int ii = 0; ii < 16; ++ii) {
        float acc = 0.0f;
#pragma unroll
        for (int k = 0; k < DD; ++k) {
            float d = ps[ii * DD + k] - qv[k];
            acc = fmaf(d, d, acc);
        }
        Kh[(size_t)(r0 + ii) * MM + j] = __float2half(__expf(-acc * INV_REG));
    }
}

// ---------------------------------------------------------------------------
// u-pass: u[i] = a / (Kh[i,:] . v16). Even t: if slot==0 (odd-parity v was
// 2-periodic) -> set sticky conv, skip. Odd t: zero slot for this iter's
// v-pass detection. 512 blocks x 512 thr, one row per wave.
// ---------------------------------------------------------------------------
__global__ void __launch_bounds__(512)
rowpass_u(const __half* __restrict__ Mat, const __half* __restrict__ w16_in,
          float* __restrict__ w32_out, __half* __restrict__ w16_out,
          unsigned* __restrict__ conv, unsigned* __restrict__ slot, int t) {
    if (ld_dev_u32(conv)) return;
    if ((t & 1) == 0) {
        if (ld_dev_u32(slot) == 0u) {   // frozen: u,v buffers already final
            if (threadIdx.x == 0) st_dev_u32(conv, 1u);
            return;
        }
    } else {
        if (blockIdx.x == 0 && threadIdx.x == 0) st_dev_u32(slot, 0u);
    }

    __shared__ __align__(16) __half vlds[MM];
    const int tid = threadIdx.x;
    ((uint4*)vlds)[tid] = ((const uint4*)w16_in)[tid];
    __syncthreads();

    const int lane = tid & 63;
    const int i    = blockIdx.x * 8 + (tid >> 6);
    const uint4* Mrow = (const uint4*)(Mat + (size_t)i * MM);
    const uint4* V    = (const uint4*)vlds;

    float acc = 0.0f;
#pragma unroll
    for (int c = 0; c < 8; ++c) {
        const int g = c * 64 + lane;
        uint4 kk = Mrow[g];
        uint4 vv = V[g];
        acc = dot2(kk.x, vv.x, acc);
        acc = dot2(kk.y, vv.y, acc);
        acc = dot2(kk.z, vv.z, acc);
        acc = dot2(kk.w, vv.w, acc);
    }
#pragma unroll
    for (int off = 32; off > 0; off >>= 1) acc += __shfl_down(acc, off, 64);
    if (lane == 0) {
        float r = A_MARG / acc;
        w32_out[i] = r;
        w16_out[i] = __float2half(r);
    }
}

// ---------------------------------------------------------------------------
// v-pass: v[j] = b / (KTh[j,:] . u16). Odd t: compare new fp16 bits against
// hist (v from t-2, same parity); any mismatch -> slot=1; update hist.
// ---------------------------------------------------------------------------
__global__ void __launch_bounds__(512)
rowpass_v(const __half* __restrict__ Mat, const __half* __restrict__ w16_in,
          float* __restrict__ w32_out, __half* __restrict__ w16_out,
          unsigned short* __restrict__ hist,
          unsigned* __restrict__ conv, unsigned* __restrict__ slot, int t) {
    if (ld_dev_u32(conv)) return;

    __shared__ __align__(16) __half vlds[MM];
    const int tid = threadIdx.x;
    ((uint4*)vlds)[tid] = ((const uint4*)w16_in)[tid];
    __syncthreads();

    const int lane = tid & 63;
    const int i    = blockIdx.x * 8 + (tid >> 6);
    const uint4* Mrow = (const uint4*)(Mat + (size_t)i * MM);
    const uint4* V    = (const uint4*)vlds;

    float acc = 0.0f;
#pragma unroll
    for (int c = 0; c < 8; ++c) {
        const int g = c * 64 + lane;
        uint4 kk = Mrow[g];
        uint4 vv = V[g];
        acc = dot2(kk.x, vv.x, acc);
        acc = dot2(kk.y, vv.y, acc);
        acc = dot2(kk.z, vv.z, acc);
        acc = dot2(kk.w, vv.w, acc);
    }
#pragma unroll
    for (int off = 32; off > 0; off >>= 1) acc += __shfl_down(acc, off, 64);
    if (lane == 0) {
        float r = B_MARG / acc;
        w32_out[i] = r;
        const __half h = __float2half(r);
        const unsigned short bits = __half_as_ushort(h);
        if (t & 1) {
            unsigned short old2 = ld_dev_u16(hist + i);
            if (old2 != bits) st_dev_u32(slot, 1u);
            st_dev_u16(hist + i, bits);
        }
        w16_out[i] = h;
    }
}

// ---------------------------------------------------------------------------
// gamma[i][j] = u[i] * exp(-||x_i-y_j||^2/reg) * v[j]   (exact fp32 K)
// grid: (16, 256), block 256
// ---------------------------------------------------------------------------
__global__ void epilogue(const float* __restrict__ x, const float* __restrict__ y,
                         const float* __restrict__ u, const float* __restrict__ v,
                         float* __restrict__ out) {
    const int tid = threadIdx.x;
    const int j   = blockIdx.x * 256 + tid;
    const int r0  = blockIdx.y * 16;

    float yv[DD];
    const float4* y4 = (const float4*)(y + (size_t)j * DD);
#pragma unroll
    for (int k = 0; k < DD / 4; ++k) {
        float4 t = y4[k];
        yv[4 * k + 0] = t.x; yv[4 * k + 1] = t.y;
        yv[4 * k + 2] = t.z; yv[4 * k + 3] = t.w;
    }

    __shared__ float xs[16 * DD];
    __shared__ float u_lds[16];
    xs[tid]       = x[(size_t)r0 * DD + tid];
    xs[tid + 256] = x[(size_t)r0 * DD + tid + 256];
    if (tid < 16) u_lds[tid] = u[r0 + tid];
    __syncthreads();

    const float vj = v[j];
#pragma unroll 4
    for (int ii = 0; ii < 16; ++ii) {
        float acc = 0.0f;
#pragma unroll
        for (int k = 0; k < DD; ++k) {
            float d = xs[ii * DD + k] - yv[k];
            acc = fmaf(d, d, acc);
        }
        out[(size_t)(r0 + ii) * MM + j] = u_lds[ii] * __expf(-acc * INV_REG) * vj;
    }
}

extern "C" void kernel_launch(void* const* d_in, const int* in_sizes, int n_in,
                              void* d_out, int out_size, void* d_ws, size_t ws_size,
                              hipStream_t stream) {
    const float* x = (const float*)d_in[0];
    const float* y = (const float*)d_in[1];
    __half*   Kh   = (__half*)d_ws;                    // 32 MB
    __half*   KTh  = Kh + (size_t)NN * MM;             // 32 MB
    float*    u32  = (float*)(KTh + (size_t)NN * MM);  // 16 KB
    float*    v32  = u32 + NN;                         // 16 KB
    __half*   u16  = (__half*)(v32 + MM);              // 8 KB
    __half*   v16  = u16 + NN;                         // 8 KB
    unsigned short* hist = (unsigned short*)(v16 + MM);// 8 KB (0xAA-poison safe)
    unsigned* conv = (unsigned*)(hist + MM);           // 4 B
    unsigned* slot = conv + 1;                         // 4 B
    float*    out  = (float*)d_out;

    compute_K_half<<<dim3(MM / 256, NN / 16), 256, 0, stream>>>(x, y, Kh, v16, conv, slot, 1);
    compute_K_half<<<dim3(NN / 256, MM / 16), 256, 0, stream>>>(y, x, KTh, v16, conv, slot, 0);

    for (int t = 0; t < N_ITERS; ++t) {
        rowpass_u<<<NN / 8, 512, 0, stream>>>(Kh,  v16, u32, u16, conv, slot, t);
        rowpass_v<<<MM / 8, 512, 0, stream>>>(KTh, u16, v32, v16, hist, conv, slot, t);
    }

    epilogue<<<dim3(MM / 256, NN / 16), 256, 0, stream>>>(x, y, u32, v32, out);
}